// Round 9
// baseline (283.537 us; speedup 1.0000x reference)
//
#include <hip/hip_runtime.h>
#include <math.h>

#define HB 8
#define KD 64
#define VD 192
#define BT 2
#define TT 1536
#define CC 1536
#define HK (HB*KD)   // 512
#define HV (HB*VD)   // 1536
#define QKVP 2560    // fused qkv row pitch: q[0:512) k[512:1024) v[1024:2560)
#define LOG2E 1.44269504088896340736f

typedef float f32x4 __attribute__((ext_vector_type(4)));
typedef __bf16 bf16x8 __attribute__((ext_vector_type(8)));

static __device__ __forceinline__ ushort f2bf(float f) {
  union { float f; uint u; } v; v.f = f;
  uint r = (v.u + 0x7FFFu + ((v.u >> 16) & 1u)) >> 16;  // RNE
  return (ushort)r;
}
static __device__ __forceinline__ float bf2f(ushort u) {
  union { uint u; float f; } v; v.u = ((uint)u) << 16; return v.f;
}

static __device__ __forceinline__ f32x4 mfma_bf(bf16x8 a, bf16x8 b, f32x4 c) {
  return __builtin_amdgcn_mfma_f32_16x16x32_bf16(a, b, c, 0, 0, 0);
}

static __device__ __forceinline__ void gload_lds16(const ushort* g, ushort* l) {
  __builtin_amdgcn_global_load_lds(
      (const __attribute__((address_space(1))) unsigned int*)g,
      (__attribute__((address_space(3))) unsigned int*)l, 16, 0, 0);
}

__device__ __forceinline__ void storeC(float* p, float v) { *p = v; }
__device__ __forceinline__ void storeC(ushort* p, float v) { *p = f2bf(v); }

// ---------------- cast fp32 -> bf16 (vectorized) ----------------
__global__ __launch_bounds__(256) void cast_bf16(
    const float* __restrict__ in, ushort* __restrict__ out, int n4)
{
  for (int i = blockIdx.x*blockDim.x + threadIdx.x; i < n4; i += gridDim.x*blockDim.x) {
    float4 v = ((const float4*)in)[i];
    ushort4 o; o.x = f2bf(v.x); o.y = f2bf(v.y); o.z = f2bf(v.z); o.w = f2bf(v.w);
    ((ushort4*)out)[i] = o;
  }
}

// ---------------- transpose + cast + scale: in[R][C] fp32 -> out[C][R] bf16 ----------------
__global__ void tcast(const float* __restrict__ in, ushort* __restrict__ out, int R, int C, float scale)
{
  __shared__ float tile[32][33];
  const int bx = blockIdx.x * 32;
  const int by = blockIdx.y * 32;
  const int tx = threadIdx.x, ty = threadIdx.y;  // (32,8)
  #pragma unroll
  for (int i = 0; i < 4; ++i)
    tile[ty + i*8][tx] = in[(size_t)(by + ty + i*8)*C + bx + tx];
  __syncthreads();
  #pragma unroll
  for (int i = 0; i < 4; ++i)
    out[(size_t)(bx + ty + i*8)*R + by + tx] = f2bf(tile[tx][ty + i*8] * scale);
}

// ---------------- bf16 transpose of V section: qkv[key][1024+vd] -> vTg[vd][key] ----------------
__global__ void vtrans(const ushort* __restrict__ in, ushort* __restrict__ out)
{
  __shared__ ushort tile[32][33];
  const int bx = blockIdx.x * 32;  // vd base
  const int by = blockIdx.y * 32;  // key base
  const int tx = threadIdx.x, ty = threadIdx.y;  // (32,8)
  #pragma unroll
  for (int i = 0; i < 4; ++i)
    tile[ty + i*8][tx] = in[(size_t)(by + ty + i*8)*QKVP + 1024 + bx + tx];
  __syncthreads();
  #pragma unroll
  for (int i = 0; i < 4; ++i)
    out[(size_t)(bx + ty + i*8)*(BT*TT) + by + tx] = tile[tx][ty + i*8];
}

// ---------------- bf16 MFMA GEMM: C[M,N] = A[M,Kd] @ Bt[N,Kd]^T (+bias) ----------------
template<bool WITH_BIAS, typename OutT>
__global__ __launch_bounds__(256) void gemm_bf16(
    const ushort* __restrict__ A, const ushort* __restrict__ Bt,
    const float* __restrict__ bias, OutT* __restrict__ C,
    int M, int N, int Kd)
{
  __shared__ __align__(16) ushort As[128*64];
  __shared__ __align__(16) ushort Bs[128*64];
  const int t = threadIdx.x;
  const int w = t >> 6, lane = t & 63;
  const int lrow = lane & 15, lk8 = lane >> 4;
  const int row0 = blockIdx.y * 128, col0 = blockIdx.x * 128;
  const int wr = (w >> 1) * 64, wc = (w & 1) * 64;

  f32x4 acc[4][4];
  #pragma unroll
  for (int m = 0; m < 4; ++m)
    #pragma unroll
    for (int n = 0; n < 4; ++n) acc[m][n] = (f32x4){0.f,0.f,0.f,0.f};

  for (int k0 = 0; k0 < Kd; k0 += 64) {
    __syncthreads();
    #pragma unroll
    for (int j = 0; j < 4; ++j) {
      const int c = (w*4 + j)*64 + lane;
      const int r = c >> 3, cp = c & 7;
      const int sc = cp ^ (r & 7);
      gload_lds16(A  + (size_t)(row0 + r)*Kd + k0 + sc*8, As + c*8);
      gload_lds16(Bt + (size_t)(col0 + r)*Kd + k0 + sc*8, Bs + c*8);
    }
    __syncthreads();
    bf16x8 af[4][2], bfv[4][2];
    #pragma unroll
    for (int m = 0; m < 4; ++m) {
      const int r = wr + m*16 + lrow;
      #pragma unroll
      for (int kh = 0; kh < 2; ++kh) {
        const int k8 = lk8 + kh*4;
        af[m][kh] = *(const bf16x8*)&As[r*64 + ((k8 ^ (r & 7)) << 3)];
      }
    }
    #pragma unroll
    for (int n = 0; n < 4; ++n) {
      const int r = wc + n*16 + lrow;
      #pragma unroll
      for (int kh = 0; kh < 2; ++kh) {
        const int k8 = lk8 + kh*4;
        bfv[n][kh] = *(const bf16x8*)&Bs[r*64 + ((k8 ^ (r & 7)) << 3)];
      }
    }
    #pragma unroll
    for (int m = 0; m < 4; ++m)
      #pragma unroll
      for (int n = 0; n < 4; ++n) {
        acc[m][n] = mfma_bf(af[m][0], bfv[n][0], acc[m][n]);
        acc[m][n] = mfma_bf(af[m][1], bfv[n][1], acc[m][n]);
      }
  }
  #pragma unroll
  for (int m = 0; m < 4; ++m)
    #pragma unroll
    for (int n = 0; n < 4; ++n) {
      const int cg = col0 + wc + n*16 + lrow;
      const float bb = WITH_BIAS ? bias[cg] : 0.f;
      #pragma unroll
      for (int r = 0; r < 4; ++r) {
        const int rg = row0 + wr + m*16 + lk8*4 + r;
        storeC(&C[(size_t)rg*N + cg], acc[m][n][r] + bb);
      }
    }
}

// ---------------- Wrk suffix sums ----------------
__global__ __launch_bounds__(256) void wrk_suffix(
    const float* __restrict__ Wrk, float* __restrict__ S1, float* __restrict__ S2)
{
  const int c = blockIdx.x*blockDim.x + threadIdx.x;
  float a1 = 0.f, a2 = 0.f;
  S1[96*HK + c] = 0.f; S2[96*HK + c] = 0.f;
  for (int i = 95; i >= 0; --i) {
    a1 += Wrk[i*HK + c];
    a2 += Wrk[(96 + i)*HK + c];
    S1[i*HK + c] = a1; S2[i*HK + c] = a2;
  }
}

// ---------------- rk[m][c] bf16 + c2[h][m] = (rrb_h . rk[m]) * log2e ----------------
__global__ __launch_bounds__(256) void relk_fill(
    const float* __restrict__ S1, const float* __restrict__ S2,
    const float* __restrict__ rrb, ushort* __restrict__ rk, float* __restrict__ c2g)
{
  __shared__ float cw[96];
  __shared__ float red[512];
  __shared__ int i0s;
  const int t = threadIdx.x;
  const int m = blockIdx.x;            // 0 .. 2T-2
  if (t < 96) {
    double pr = exp(log((double)(TT + 1)) / 96.0);
    float prf = (float)pr;
    cw[t] = (float)pow((double)prf, (double)(t + 1)) - 1.0f;
  }
  __syncthreads();
  const int d = m - (TT - 1);
  const float ad = fabsf((float)d);
  if (t == 0) {
    int i0 = 96;
    for (int i = 0; i < 96; ++i) if (cw[i] > ad) { i0 = i; break; }
    i0s = i0;
  }
  __syncthreads();
  const float sg = (d > 0) ? 1.f : (d < 0 ? -1.f : 0.f);
  const int i0 = i0s;
  for (int c = t; c < HK; c += 256) {
    const float val = S1[i0*HK + c] + sg * S2[i0*HK + c];
    const ushort vb = f2bf(val);
    rk[(size_t)m * HK + c] = vb;
    red[c] = bf2f(vb) * rrb[c];
  }
  __syncthreads();
  if (t < 8) {
    float s = 0.f;
    #pragma unroll 16
    for (int i = 0; i < 64; ++i) s += red[t*64 + i];
    c2g[(size_t)t*(2*TT - 1) + m] = s * LOG2E;
  }
}

// ---------------- c1[h][row] = (rwb_h . k[row]) * log2e ----------------
__global__ __launch_bounds__(256) void c1_kernel(
    const ushort* __restrict__ qkv, const float* __restrict__ rwb, float* __restrict__ c1g)
{
  const int idx = blockIdx.x*256 + threadIdx.x;  // 3072*8
  const int h = idx & 7, row = idx >> 3;
  const ushort* kr = &qkv[(size_t)row*QKVP + 512 + h*KD];
  float s = 0.f;
  #pragma unroll 16
  for (int c = 0; c < 64; ++c) s += bf2f(kr[c]) * rwb[h*KD + c];
  c1g[h*(BT*TT) + row] = s * LOG2E;
}

// ---------------- fused relative attention: KBLK=64, LDS-staging-free (L2-direct B-frags) ----------------
__global__ __launch_bounds__(256, 4) void attn_mfma(
    const ushort* __restrict__ qkv, const ushort* __restrict__ vTg,
    const ushort* __restrict__ rk,
    const float* __restrict__ c1g, const float* __restrict__ c2g,
    ushort* __restrict__ aout)
{
  __shared__ __align__(16) float S1[32][68];     // content logits (8.5 KB)
  __shared__ __align__(16) float S2[32][98];     // rel logits, 95-wide band (12.25 KB)
  __shared__ __align__(16) ushort Pl[32][72];    // probabilities bf16 (4.5 KB)
  __shared__ float corrl[32], linv[32];

  const int t = threadIdx.x;
  const int wv = t >> 6, lane = t & 63;
  const int lrow = lane & 15, lk8 = lane >> 4;
  const int bid = blockIdx.x;
  const int qt = bid % (TT/32);
  const int h  = (bid / (TT/32)) % HB;
  const int b  = bid / ((TT/32) * HB);
  const int q0 = qt * 32;

  // q A-fragments (loop-invariant; named regs -> cndmask select, no scratch)
  bf16x8 af00, af01, af10, af11;
  {
    const ushort* qbase = &qkv[((size_t)(b*TT) + q0 + lrow)*QKVP + h*KD];
    af00 = *(const bf16x8*)&qbase[lk8*8];
    af01 = *(const bf16x8*)&qbase[32 + lk8*8];
    af10 = *(const bf16x8*)&qbase[16*QKVP + lk8*8];
    af11 = *(const bf16x8*)&qbase[16*QKVP + 32 + lk8*8];
  }

  // per-thread S tile columns (loop-invariant)
  int jk_[2], rt1_[2], j2_[3], rt2_[3];
  #pragma unroll
  for (int s = 0; s < 2; ++s) {
    const int idx = wv*2 + s;
    rt1_[s] = idx >> 2; jk_[s] = (idx & 3)*16 + lrow;
  }
  #pragma unroll
  for (int s = 0; s < 3; ++s) {
    const int idx = wv*3 + s;
    rt2_[s] = (idx >= 6) ? 1 : 0; j2_[s] = (idx - 6*rt2_[s])*16 + lrow;
  }

  // loop-invariant global base pointers
  const ushort* kbase = qkv + (size_t)(b*TT)*QKVP + 512 + h*KD;          // + key*QKVP + k8
  const ushort* rbase = rk + (size_t)(1504 - q0)*HK + h*KD;              // + (kt0+j2)*HK + k8 (clamped)
  const ushort* vbase = vTg + (size_t)(h*VD)*(BT*TT) + b*TT;             // + vd*(BT*TT) + key

  f32x4 acc[2][3];
  #pragma unroll
  for (int i = 0; i < 2; ++i)
    #pragma unroll
    for (int j = 0; j < 3; ++j) acc[i][j] = (f32x4){0.f, 0.f, 0.f, 0.f};
  float m_i = -1e30f, l_i = 0.f;
  const int r_s = t >> 3;
  const int vsl = t & 7;

  for (int it = 0; it < 24; ++it) {
    const int kt0 = it << 6;
    const int mb = kt0 - q0 + 1504;   // S2 band global row base (rk row = mb - 1504 + 1504 + j2... = kt0-q0+1504+j2)
    // ---- c1/c2 scalar loads (L1/L2-resident small arrays) ----
    float c1p[2], c2p[3];
    #pragma unroll
    for (int s = 0; s < 2; ++s) c1p[s] = c1g[h*(BT*TT) + b*TT + kt0 + jk_[s]];
    #pragma unroll
    for (int s = 0; s < 3; ++s) {
      const float v = c2g[(size_t)h*(2*TT - 1) + (kt0 - q0 + 1504) + (j2_[s] < 95 ? j2_[s] : 94)];
      c2p[s] = (j2_[s] < 95) ? v : 0.f;
    }
    // ---- S-phase: B-fragments straight from global (L2) ----
    #pragma unroll
    for (int s = 0; s < 2; ++s) {
      const int rt = rt1_[s], jk = jk_[s];
      const ushort* kr = kbase + (size_t)(kt0 + jk)*QKVP;
      bf16x8 b0 = *(const bf16x8*)&kr[lk8*8];
      bf16x8 b1 = *(const bf16x8*)&kr[32 + lk8*8];
      const bf16x8 a0 = rt ? af10 : af00;
      const bf16x8 a1 = rt ? af11 : af01;
      f32x4 c0 = (f32x4){0.f, 0.f, 0.f, 0.f};
      c0 = mfma_bf(a0, b0, c0);
      c0 = mfma_bf(a1, b1, c0);
      #pragma unroll
      for (int r = 0; r < 4; ++r) S1[rt*16 + lk8*4 + r][jk] = c0[r] + c1p[s];
    }
    #pragma unroll
    for (int s = 0; s < 3; ++s) {
      const int rt = rt2_[s], j2 = j2_[s];
      const int grow = kt0 + (j2 < 95 ? j2 : 94);   // clamp: col 95 never read
      const ushort* rr = rbase + (size_t)grow*HK;
      bf16x8 b0 = *(const bf16x8*)&rr[lk8*8];
      bf16x8 b1 = *(const bf16x8*)&rr[32 + lk8*8];
      const bf16x8 a0 = rt ? af10 : af00;
      const bf16x8 a1 = rt ? af11 : af01;
      f32x4 c0 = (f32x4){0.f, 0.f, 0.f, 0.f};
      c0 = mfma_bf(a0, b0, c0);
      c0 = mfma_bf(a1, b1, c0);
      #pragma unroll
      for (int r = 0; r < 4; ++r) S2[rt*16 + lk8*4 + r][j2] = c0[r] + c2p[s];
    }
    __syncthreads();
    // ---- online softmax (exp2 domain, defer-max THR=8) ----
    {
      float sv[8];
      #pragma unroll
      for (int i = 0; i < 8; ++i) {
        const int j = vsl*8 + i;
        sv[i] = S1[r_s][j] + S2[r_s][j - r_s + 31];
      }
      float lmax = sv[0];
      #pragma unroll
      for (int i = 1; i < 8; ++i) lmax = fmaxf(lmax, sv[i]);
      #pragma unroll
      for (int s = 1; s < 8; s <<= 1) lmax = fmaxf(lmax, __shfl_xor(lmax, s, 64));
      const bool defer = (lmax <= m_i + 8.0f);
      const float m_new = defer ? m_i : fmaxf(m_i, lmax);
      const float corr  = defer ? 1.0f : exp2f(m_i - m_new);
      float p[8];
      float lsum = 0.f;
      #pragma unroll
      for (int i = 0; i < 8; ++i) { p[i] = exp2f(sv[i] - m_new); lsum += p[i]; }
      uint4 pw;
      pw.x = (uint)f2bf(p[0]) | ((uint)f2bf(p[1]) << 16);
      pw.y = (uint)f2bf(p[2]) | ((uint)f2bf(p[3]) << 16);
      pw.z = (uint)f2bf(p[4]) | ((uint)f2bf(p[5]) << 16);
      pw.w = (uint)f2bf(p[6]) | ((uint)f2bf(p[7]) << 16);
      *(uint4*)&Pl[r_s][vsl*8] = pw;
      #pragma unroll
      for (int s = 1; s < 8; s <<= 1) lsum += __shfl_xor(lsum, s, 64);
      l_i = l_i * corr + lsum;
      m_i = m_new;
      if (vsl == 0) corrl[r_s] = corr;
    }
    __syncthreads();
    // ---- PV: V B-fragments straight from global (L2) ----
    {
      bf16x8 pa[2][2], bv[3][2];
      #pragma unroll
      for (int rt = 0; rt < 2; ++rt) {
        pa[rt][0] = *(const bf16x8*)&Pl[rt*16 + lrow][lk8*8];
        pa[rt][1] = *(const bf16x8*)&Pl[rt*16 + lrow][32 + lk8*8];
      }
      #pragma unroll
      for (int cc = 0; cc < 3; ++cc) {
        const int rv = (3*wv + cc)*16 + lrow;
        const ushort* vr = vbase + (size_t)rv*(BT*TT) + kt0;
        bv[cc][0] = *(const bf16x8*)&vr[lk8*8];
        bv[cc][1] = *(const bf16x8*)&vr[32 + lk8*8];
      }
      float cr[2][4];
      #pragma unroll
      for (int rt = 0; rt < 2; ++rt)
        #pragma unroll
        for (int r = 0; r < 4; ++r) cr[rt][r] = corrl[rt*16 + lk8*4 + r];
      bool need = false;
      #pragma unroll
      for (int rt = 0; rt < 2; ++rt)
        #pragma unroll
        for (int r = 0; r < 4; ++r) need |= (cr[rt][r] != 1.0f);
      if (__any(need ? 1 : 0)) {
        #pragma unroll
        for (int rt = 0; rt < 2; ++rt)
          #pragma unroll
          for (int cc = 0; cc < 3; ++cc)
            #pragma unroll
            for (int r = 0; r < 4; ++r) acc[rt][cc][r] *= cr[rt][r];
      }
      #pragma unroll
      for (int rt = 0; rt < 2; ++rt)
        #pragma unroll
        for (int cc = 0; cc < 3; ++cc) {
          acc[rt][cc] = mfma_bf(pa[rt][0], bv[cc][0], acc[rt][cc]);
          acc[rt][cc] = mfma_bf(pa[rt][1], bv[cc][1], acc[rt][cc]);
        }
    }
  }
  if (vsl == 0) linv[r_s] = 1.0f / l_i;
  __syncthreads();
  #pragma unroll
  for (int rt = 0; rt < 2; ++rt) {
    #pragma unroll
    for (int cc = 0; cc < 3; ++cc) {
      const int colg = (3*wv + cc)*16 + lrow;
      #pragma unroll
      for (int r = 0; r < 4; ++r) {
        const int rowg = rt*16 + lk8*4 + r;
        aout[((size_t)(b*TT) + q0 + rowg) * HV + h*VD + colg] = f2bf(acc[rt][cc][r] * linv[rowg]);
      }
    }
  }
}

extern "C" void kernel_launch(void* const* d_in, const int* in_sizes, int n_in,
                              void* d_out, int out_size, void* d_ws, size_t ws_size,
                              hipStream_t stream)
{
  const float* X   = (const float*)d_in[0];
  const float* Wq  = (const float*)d_in[1];
  const float* Wk  = (const float*)d_in[2];
  const float* Wv  = (const float*)d_in[3];
  const float* Wrk = (const float*)d_in[4];
  const float* We  = (const float*)d_in[5];
  const float* be  = (const float*)d_in[6];
  const float* rwb = (const float*)d_in[7];
  const float* rrb = (const float*)d_in[8];
  float* out = (float*)d_out;

  char* ws = (char*)d_ws;
  ushort* Xb    = (ushort*)ws;                       ws += (size_t)3072*1536*2;
  ushort* Wqkvt = (ushort*)ws;                       ws += (size_t)2560*1536*2;
  ushort* Wet   = (ushort*)ws;                       ws += (size_t)1536*1536*2;
  float*  S1b   = (float*)ws;                        ws += (size_t)97*512*4;
  float*  S2b   = (float*)ws;                        ws += (size_t)97*512*4;
  ushort* qkvb  = (ushort*)ws;                       ws += (size_t)3072*2560*2;
  ushort* vTgb  = (ushort*)ws;                       ws += (size_t)1536*3072*2;
  ushort* rkb   = (ushort*)ws;                       ws += (size_t)3071*512*2;
  float*  c1g   = (float*)ws;                        ws += (size_t)8*3072*4;
  float*  c2g   = (float*)ws;                        ws += (size_t)8*3071*4;
  ushort* ao    = (ushort*)ws;                       // 3072*1536*2

  dim3 blk(256);
  cast_bf16<<<2048, blk, 0, stream>>>(X, Xb, (3072*1536)/4);
  tcast<<<dim3(512/32, 1536/32),  dim3(32,8), 0, stream>>>(Wq, Wqkvt,                      1536, 512,  0.125f*LOG2E);
  tcast<<<dim3(512/32, 1536/32),  dim3(32,8), 0, stream>>>(Wk, Wqkvt + (size_t)512*1536,   1536, 512,  1.0f);
  tcast<<<dim3(1536/32, 1536/32), dim3(32,8), 0, stream>>>(Wv, Wqkvt + (size_t)1024*1536,  1536, 1536, 1.0f);
  tcast<<<dim3(1536/32, 1536/32), dim3(32,8), 0, stream>>>(We, Wet, 1536, 1536, 1.0f);
  wrk_suffix<<<2, blk, 0, stream>>>(Wrk, S1b, S2b);
  relk_fill<<<dim3(2*TT - 1), blk, 0, stream>>>(S1b, S2b, rrb, rkb, c2g);
  gemm_bf16<false, ushort><<<dim3(20, 24), blk, 0, stream>>>(Xb, Wqkvt, nullptr, qkvb, 3072, QKVP, 1536);
  vtrans<<<dim3(1536/32, 3072/32), dim3(32,8), 0, stream>>>(qkvb, vTgb);
  c1_kernel<<<96, blk, 0, stream>>>(qkvb, rwb, c1g);
  attn_mfma<<<dim3(BT*HB*(TT/32)), blk, 0, stream>>>(qkvb, vTgb, rkb, c1g, c2g, ao);
  gemm_bf16<true, float><<<dim3(12, 24), blk, 0, stream>>>(ao, Wet, be, out, 3072, 1536, 1536);
}

// Round 10
// 256.490 us; speedup vs baseline: 1.1054x; 1.1054x over previous
//
#include <hip/hip_runtime.h>
#include <math.h>

#define HB 8
#define KD 64
#define VD 192
#define BT 2
#define TT 1536
#define CC 1536
#define HK (HB*KD)   // 512
#define HV (HB*VD)   // 1536
#define QKVP 2560    // fused qkv row pitch: q[0:512) k[512:1024) v[1024:2560)
#define LOG2E 1.44269504088896340736f

typedef float f32x4 __attribute__((ext_vector_type(4)));
typedef __bf16 bf16x8 __attribute__((ext_vector_type(8)));

static __device__ __forceinline__ ushort f2bf(float f) {
  union { float f; uint u; } v; v.f = f;
  uint r = (v.u + 0x7FFFu + ((v.u >> 16) & 1u)) >> 16;  // RNE
  return (ushort)r;
}
static __device__ __forceinline__ float bf2f(ushort u) {
  union { uint u; float f; } v; v.u = ((uint)u) << 16; return v.f;
}

static __device__ __forceinline__ f32x4 mfma_bf(bf16x8 a, bf16x8 b, f32x4 c) {
  return __builtin_amdgcn_mfma_f32_16x16x32_bf16(a, b, c, 0, 0, 0);
}

static __device__ __forceinline__ void gload_lds16(const ushort* g, ushort* l) {
  __builtin_amdgcn_global_load_lds(
      (const __attribute__((address_space(1))) unsigned int*)g,
      (__attribute__((address_space(3))) unsigned int*)l, 16, 0, 0);
}

__device__ __forceinline__ void storeC(float* p, float v) { *p = v; }
__device__ __forceinline__ void storeC(ushort* p, float v) { *p = f2bf(v); }

// ---------------- cast fp32 -> bf16 (vectorized) ----------------
__global__ __launch_bounds__(256) void cast_bf16(
    const float* __restrict__ in, ushort* __restrict__ out, int n4)
{
  for (int i = blockIdx.x*blockDim.x + threadIdx.x; i < n4; i += gridDim.x*blockDim.x) {
    float4 v = ((const float4*)in)[i];
    ushort4 o; o.x = f2bf(v.x); o.y = f2bf(v.y); o.z = f2bf(v.z); o.w = f2bf(v.w);
    ((ushort4*)out)[i] = o;
  }
}

// ---------------- transpose + cast + scale: in[R][C] fp32 -> out[C][R] bf16 ----------------
__global__ void tcast(const float* __restrict__ in, ushort* __restrict__ out, int R, int C, float scale)
{
  __shared__ float tile[32][33];
  const int bx = blockIdx.x * 32;
  const int by = blockIdx.y * 32;
  const int tx = threadIdx.x, ty = threadIdx.y;  // (32,8)
  #pragma unroll
  for (int i = 0; i < 4; ++i)
    tile[ty + i*8][tx] = in[(size_t)(by + ty + i*8)*C + bx + tx];
  __syncthreads();
  #pragma unroll
  for (int i = 0; i < 4; ++i)
    out[(size_t)(bx + ty + i*8)*R + by + tx] = f2bf(tile[tx][ty + i*8] * scale);
}

// ---------------- bf16 transpose of V section: qkv[key][1024+vd] -> vTg[vd][key] ----------------
__global__ void vtrans(const ushort* __restrict__ in, ushort* __restrict__ out)
{
  __shared__ ushort tile[32][33];
  const int bx = blockIdx.x * 32;  // vd base
  const int by = blockIdx.y * 32;  // key base
  const int tx = threadIdx.x, ty = threadIdx.y;  // (32,8)
  #pragma unroll
  for (int i = 0; i < 4; ++i)
    tile[ty + i*8][tx] = in[(size_t)(by + ty + i*8)*QKVP + 1024 + bx + tx];
  __syncthreads();
  #pragma unroll
  for (int i = 0; i < 4; ++i)
    out[(size_t)(bx + ty + i*8)*(BT*TT) + by + tx] = tile[tx][ty + i*8];
}

// ---------------- bf16 MFMA GEMM: C[M,N] = A[M,Kd] @ Bt[N,Kd]^T (+bias) ----------------
template<bool WITH_BIAS, typename OutT>
__global__ __launch_bounds__(256) void gemm_bf16(
    const ushort* __restrict__ A, const ushort* __restrict__ Bt,
    const float* __restrict__ bias, OutT* __restrict__ C,
    int M, int N, int Kd)
{
  __shared__ __align__(16) ushort As[128*64];
  __shared__ __align__(16) ushort Bs[128*64];
  const int t = threadIdx.x;
  const int w = t >> 6, lane = t & 63;
  const int lrow = lane & 15, lk8 = lane >> 4;
  const int row0 = blockIdx.y * 128, col0 = blockIdx.x * 128;
  const int wr = (w >> 1) * 64, wc = (w & 1) * 64;

  f32x4 acc[4][4];
  #pragma unroll
  for (int m = 0; m < 4; ++m)
    #pragma unroll
    for (int n = 0; n < 4; ++n) acc[m][n] = (f32x4){0.f,0.f,0.f,0.f};

  for (int k0 = 0; k0 < Kd; k0 += 64) {
    __syncthreads();
    #pragma unroll
    for (int j = 0; j < 4; ++j) {
      const int c = (w*4 + j)*64 + lane;
      const int r = c >> 3, cp = c & 7;
      const int sc = cp ^ (r & 7);
      gload_lds16(A  + (size_t)(row0 + r)*Kd + k0 + sc*8, As + c*8);
      gload_lds16(Bt + (size_t)(col0 + r)*Kd + k0 + sc*8, Bs + c*8);
    }
    __syncthreads();
    bf16x8 af[4][2], bfv[4][2];
    #pragma unroll
    for (int m = 0; m < 4; ++m) {
      const int r = wr + m*16 + lrow;
      #pragma unroll
      for (int kh = 0; kh < 2; ++kh) {
        const int k8 = lk8 + kh*4;
        af[m][kh] = *(const bf16x8*)&As[r*64 + ((k8 ^ (r & 7)) << 3)];
      }
    }
    #pragma unroll
    for (int n = 0; n < 4; ++n) {
      const int r = wc + n*16 + lrow;
      #pragma unroll
      for (int kh = 0; kh < 2; ++kh) {
        const int k8 = lk8 + kh*4;
        bfv[n][kh] = *(const bf16x8*)&Bs[r*64 + ((k8 ^ (r & 7)) << 3)];
      }
    }
    #pragma unroll
    for (int m = 0; m < 4; ++m)
      #pragma unroll
      for (int n = 0; n < 4; ++n) {
        acc[m][n] = mfma_bf(af[m][0], bfv[n][0], acc[m][n]);
        acc[m][n] = mfma_bf(af[m][1], bfv[n][1], acc[m][n]);
      }
  }
  #pragma unroll
  for (int m = 0; m < 4; ++m)
    #pragma unroll
    for (int n = 0; n < 4; ++n) {
      const int cg = col0 + wc + n*16 + lrow;
      const float bb = WITH_BIAS ? bias[cg] : 0.f;
      #pragma unroll
      for (int r = 0; r < 4; ++r) {
        const int rg = row0 + wr + m*16 + lk8*4 + r;
        storeC(&C[(size_t)rg*N + cg], acc[m][n][r] + bb);
      }
    }
}

// ---------------- Wrk suffix sums ----------------
__global__ __launch_bounds__(256) void wrk_suffix(
    const float* __restrict__ Wrk, float* __restrict__ S1, float* __restrict__ S2)
{
  const int c = blockIdx.x*blockDim.x + threadIdx.x;
  float a1 = 0.f, a2 = 0.f;
  S1[96*HK + c] = 0.f; S2[96*HK + c] = 0.f;
  for (int i = 95; i >= 0; --i) {
    a1 += Wrk[i*HK + c];
    a2 += Wrk[(96 + i)*HK + c];
    S1[i*HK + c] = a1; S2[i*HK + c] = a2;
  }
}

// ---------------- rk[m][c] bf16 + c2[h][m] = (rrb_h . rk[m]) * log2e ----------------
__global__ __launch_bounds__(256) void relk_fill(
    const float* __restrict__ S1, const float* __restrict__ S2,
    const float* __restrict__ rrb, ushort* __restrict__ rk, float* __restrict__ c2g)
{
  __shared__ float cw[96];
  __shared__ float red[512];
  __shared__ int i0s;
  const int t = threadIdx.x;
  const int m = blockIdx.x;            // 0 .. 2T-2
  if (t < 96) {
    double pr = exp(log((double)(TT + 1)) / 96.0);
    float prf = (float)pr;
    cw[t] = (float)pow((double)prf, (double)(t + 1)) - 1.0f;
  }
  __syncthreads();
  const int d = m - (TT - 1);
  const float ad = fabsf((float)d);
  if (t == 0) {
    int i0 = 96;
    for (int i = 0; i < 96; ++i) if (cw[i] > ad) { i0 = i; break; }
    i0s = i0;
  }
  __syncthreads();
  const float sg = (d > 0) ? 1.f : (d < 0 ? -1.f : 0.f);
  const int i0 = i0s;
  for (int c = t; c < HK; c += 256) {
    const float val = S1[i0*HK + c] + sg * S2[i0*HK + c];
    const ushort vb = f2bf(val);
    rk[(size_t)m * HK + c] = vb;
    red[c] = bf2f(vb) * rrb[c];
  }
  __syncthreads();
  if (t < 8) {
    float s = 0.f;
    #pragma unroll 16
    for (int i = 0; i < 64; ++i) s += red[t*64 + i];
    c2g[(size_t)t*(2*TT - 1) + m] = s * LOG2E;
  }
}

// ---------------- c1[h][row] = (rwb_h . k[row]) * log2e ----------------
__global__ __launch_bounds__(256) void c1_kernel(
    const ushort* __restrict__ qkv, const float* __restrict__ rwb, float* __restrict__ c1g)
{
  const int idx = blockIdx.x*256 + threadIdx.x;  // 3072*8
  const int h = idx & 7, row = idx >> 3;
  const ushort* kr = &qkv[(size_t)row*QKVP + 512 + h*KD];
  float s = 0.f;
  #pragma unroll 16
  for (int c = 0; c < 64; ++c) s += bf2f(kr[c]) * rwb[h*KD + c];
  c1g[h*(BT*TT) + row] = s * LOG2E;
}

// ---------------- fused relative attention: KBLK=32, register softmax, 3 barriers/iter ----------------
__global__ __launch_bounds__(256, 3) void attn_mfma(
    const ushort* __restrict__ qkv, const ushort* __restrict__ vTg,
    const ushort* __restrict__ rk,
    const float* __restrict__ c1g, const float* __restrict__ c2g,
    ushort* __restrict__ aout)
{
  __shared__ __align__(16) ushort ktL[32*64];    // k tile (4 KB)
  __shared__ __align__(16) ushort rkbL[64*64];   // rk band (8 KB), row 63 zero
  __shared__ __align__(16) ushort vTl[192*32];   // vT tile (12 KB)
  __shared__ __align__(16) float S1[32][36];     // pitch 36 f32 = 144 B (16B-mult)
  __shared__ __align__(16) float S2[32][68];     // pitch 68 f32 = 272 B (16B-mult)

  const int t = threadIdx.x;
  const int wv = t >> 6, lane = t & 63;
  const int lrow = lane & 15, lk8 = lane >> 4;
  const int bid = blockIdx.x;
  const int qt = bid % (TT/32);
  const int h  = (bid / (TT/32)) % HB;
  const int b  = bid / ((TT/32) * HB);
  const int q0 = qt * 32;

  // q A-fragments (loop-invariant; named regs)
  bf16x8 af00, af01, af10, af11;
  {
    const ushort* qbase = &qkv[((size_t)(b*TT) + q0 + lrow)*QKVP + h*KD];
    af00 = *(const bf16x8*)&qbase[lk8*8];
    af01 = *(const bf16x8*)&qbase[32 + lk8*8];
    af10 = *(const bf16x8*)&qbase[16*QKVP + lk8*8];
    af11 = *(const bf16x8*)&qbase[16*QKVP + 32 + lk8*8];
  }
  if (t < 32) ((uint*)rkbL)[63*32 + t] = 0;   // zero rk-band pad row 63

  // ---- per-thread DMA pointers ----
  const int kc_r = t >> 3, kc_p = t & 7;
  const ushort* ksrc = qkv + (size_t)(b*TT + kc_r)*QKVP + 512 + h*KD + (kc_p ^ (kc_r & 7))*8;
  ushort* kdst = ktL + t*8;
  const int rr0 = t >> 3, rr1 = (256 + t) >> 3, rpc = t & 7;
  const ushort* rsrc0 = rk + (size_t)(1504 - q0 + rr0)*HK + h*KD + (rpc ^ (rr0 & 7))*8;
  const ushort* rsrc1 = rk + (size_t)(1504 - q0 + rr1)*HK + h*KD + (rpc ^ (rr1 & 7))*8;
  ushort* rdst0 = rkbL + t*8;
  ushort* rdst1 = rkbL + (256 + t)*8;
  const bool rval = t < 248;
  const ushort* vsrc[3]; ushort* vdst[3];
  #pragma unroll
  for (int W = 0; W < 3; ++W) {
    const int c = W*256 + t;
    const int vd = c >> 2, cpk = c & 3;
    vsrc[W] = vTg + (size_t)(h*VD + vd)*(BT*TT) + b*TT + ((cpk ^ (vd & 3)))*8;
    vdst[W] = vTl + c*8;
  }

  // per-thread S-phase columns (loop-invariant)
  const int jk  = (wv & 1)*16 + lrow;   // S1 col
  const int j2a = (wv & 1)*32 + lrow;   // S2 col (s2=0)
  const int j2b = j2a + 16;             // S2 col (s2=1)
  const int rt_ = wv >> 1;

  f32x4 acc[2][3];
  #pragma unroll
  for (int i = 0; i < 2; ++i)
    #pragma unroll
    for (int j = 0; j < 3; ++j) acc[i][j] = (f32x4){0.f, 0.f, 0.f, 0.f};
  float m_i[2] = {-1e30f, -1e30f};
  float l_i[2] = {0.f, 0.f};

  // ---- prologue: issue k,r,r; load c(it0); issue v,v,v ----
  float c1v, c2v0, c2v1;
  gload_lds16(ksrc, kdst);               ksrc += 32*QKVP;
  gload_lds16(rsrc0, rdst0);             rsrc0 += 32*HK;
  if (rval) gload_lds16(rsrc1, rdst1);
  rsrc1 += 32*HK;
  {
    const int mb = -q0 + 1504;
    c1v  = c1g[h*(BT*TT) + b*TT + jk];
    c2v0 = c2g[(size_t)h*(2*TT - 1) + mb + j2a];
    const float cr = c2g[(size_t)h*(2*TT - 1) + mb + (j2b < 63 ? j2b : 62)];
    c2v1 = (j2b < 63) ? cr : 0.f;
  }
  #pragma unroll
  for (int W = 0; W < 3; ++W) { gload_lds16(vsrc[W], vdst[W]); vsrc[W] += 32; }

  for (int it = 0; it < 48; ++it) {
    // ==== A: k/rkb retired (c auto-waited at use; v flies); all-wave staging visible ====
    asm volatile("s_waitcnt vmcnt(6)" ::: "memory");
    __builtin_amdgcn_s_barrier();
    // ---- S-phase ----
    {
      const bf16x8 a0 = rt_ ? af10 : af00;
      const bf16x8 a1 = rt_ ? af11 : af01;
      bf16x8 b0 = *(const bf16x8*)&ktL[jk*64 + ((lk8 ^ (jk & 7)) << 3)];
      bf16x8 b1 = *(const bf16x8*)&ktL[jk*64 + (((lk8 + 4) ^ (jk & 7)) << 3)];
      f32x4 c0 = (f32x4){0.f, 0.f, 0.f, 0.f};
      c0 = mfma_bf(a0, b0, c0);
      c0 = mfma_bf(a1, b1, c0);
      #pragma unroll
      for (int r = 0; r < 4; ++r) S1[rt_*16 + lk8*4 + r][jk] = c0[r] + c1v;

      bf16x8 d0 = *(const bf16x8*)&rkbL[j2a*64 + ((lk8 ^ (j2a & 7)) << 3)];
      bf16x8 d1 = *(const bf16x8*)&rkbL[j2a*64 + (((lk8 + 4) ^ (j2a & 7)) << 3)];
      f32x4 ca = (f32x4){0.f, 0.f, 0.f, 0.f};
      ca = mfma_bf(a0, d0, ca);
      ca = mfma_bf(a1, d1, ca);
      #pragma unroll
      for (int r = 0; r < 4; ++r) S2[rt_*16 + lk8*4 + r][j2a] = ca[r] + c2v0;

      bf16x8 e0 = *(const bf16x8*)&rkbL[j2b*64 + ((lk8 ^ (j2b & 7)) << 3)];
      bf16x8 e1 = *(const bf16x8*)&rkbL[j2b*64 + (((lk8 + 4) ^ (j2b & 7)) << 3)];
      f32x4 cb = (f32x4){0.f, 0.f, 0.f, 0.f};
      cb = mfma_bf(a0, e0, cb);
      cb = mfma_bf(a1, e1, cb);
      #pragma unroll
      for (int r = 0; r < 4; ++r) S2[rt_*16 + lk8*4 + r][j2b] = cb[r] + c2v1;
    }
    asm volatile("s_waitcnt lgkmcnt(0)" ::: "memory");
    __builtin_amdgcn_s_barrier();   // B2: S visible; kt/rkb reads done
    // ---- issue next k/rkb + c prefetch ----
    if (it < 47) {
      gload_lds16(ksrc, kdst);               ksrc += 32*QKVP;
      gload_lds16(rsrc0, rdst0);             rsrc0 += 32*HK;
      if (rval) gload_lds16(rsrc1, rdst1);
      rsrc1 += 32*HK;
      const int kt0n = (it + 1) << 5;
      const int mbn = kt0n - q0 + 1504;
      c1v  = c1g[h*(BT*TT) + b*TT + kt0n + jk];
      c2v0 = c2g[(size_t)h*(2*TT - 1) + mbn + j2a];
      const float cr = c2g[(size_t)h*(2*TT - 1) + mbn + (j2b < 63 ? j2b : 62)];
      c2v1 = (j2b < 63) ? cr : 0.f;
    }
    // ---- in-register wave-local softmax: lane owns P rows {lrow,16+lrow} x cols lk8*8..+7 ----
    bf16x8 pa[2];
    float corr[2];
    #pragma unroll
    for (int rt = 0; rt < 2; ++rt) {
      const int row = rt*16 + lrow;
      const float4 a0 = *(const float4*)&S1[row][lk8*8];
      const float4 a1 = *(const float4*)&S1[row][lk8*8 + 4];
      const int off = lk8*8 - row + 31;      // in [0,55]
      float sv[8];
      sv[0] = a0.x + S2[row][off + 0]; sv[1] = a0.y + S2[row][off + 1];
      sv[2] = a0.z + S2[row][off + 2]; sv[3] = a0.w + S2[row][off + 3];
      sv[4] = a1.x + S2[row][off + 4]; sv[5] = a1.y + S2[row][off + 5];
      sv[6] = a1.z + S2[row][off + 6]; sv[7] = a1.w + S2[row][off + 7];
      float lm = fmaxf(fmaxf(fmaxf(sv[0], sv[1]), fmaxf(sv[2], sv[3])),
                       fmaxf(fmaxf(sv[4], sv[5]), fmaxf(sv[6], sv[7])));
      lm = fmaxf(lm, __shfl_xor(lm, 16, 64));
      lm = fmaxf(lm, __shfl_xor(lm, 32, 64));
      const bool defer = (lm <= m_i[rt] + 8.0f);
      const float m_new = defer ? m_i[rt] : fmaxf(m_i[rt], lm);
      corr[rt] = defer ? 1.0f : exp2f(m_i[rt] - m_new);
      float p[8], ls = 0.f;
      #pragma unroll
      for (int i = 0; i < 8; ++i) { p[i] = exp2f(sv[i] - m_new); ls += p[i]; }
      ls += __shfl_xor(ls, 16, 64);
      ls += __shfl_xor(ls, 32, 64);
      l_i[rt] = l_i[rt] * corr[rt] + ls;
      m_i[rt] = m_new;
      union { uint4 u; bf16x8 v; } pk;
      pk.u.x = (uint)f2bf(p[0]) | ((uint)f2bf(p[1]) << 16);
      pk.u.y = (uint)f2bf(p[2]) | ((uint)f2bf(p[3]) << 16);
      pk.u.z = (uint)f2bf(p[4]) | ((uint)f2bf(p[5]) << 16);
      pk.u.w = (uint)f2bf(p[6]) | ((uint)f2bf(p[7]) << 16);
      pa[rt] = pk.v;
    }
    // corr for accumulator rows via intra-wave shuffle
    float cracc[2][4];
    #pragma unroll
    for (int rt = 0; rt < 2; ++rt)
      #pragma unroll
      for (int r = 0; r < 4; ++r) cracc[rt][r] = __shfl(corr[rt], lk8*4 + r, 64);
    // ---- retire vT, read PV B-fragments, recycle buffer ----
    if (it < 47) { asm volatile("s_waitcnt vmcnt(6)" ::: "memory"); }
    else         { asm volatile("s_waitcnt vmcnt(0)" ::: "memory"); }
    __builtin_amdgcn_s_barrier();   // B1': vT staged for all waves
    bf16x8 bv[3];
    #pragma unroll
    for (int cc = 0; cc < 3; ++cc) {
      const int rv = (3*wv + cc)*16 + lrow;
      bv[cc] = *(const bf16x8*)&vTl[rv*32 + ((lk8 ^ (rv & 3)) << 3)];
    }
    asm volatile("s_waitcnt lgkmcnt(0)" ::: "memory");
    __builtin_amdgcn_s_barrier();   // B3: all vT reads done -> safe to restage
    if (it < 47) {
      #pragma unroll
      for (int W = 0; W < 3; ++W) { gload_lds16(vsrc[W], vdst[W]); vsrc[W] += 32; }
    }
    // ---- rescale + PV MFMAs ----
    #pragma unroll
    for (int rt = 0; rt < 2; ++rt)
      #pragma unroll
      for (int cc = 0; cc < 3; ++cc) {
        f32x4 a = acc[rt][cc];
        #pragma unroll
        for (int r = 0; r < 4; ++r) a[r] *= cracc[rt][r];
        acc[rt][cc] = mfma_bf(pa[rt], bv[cc], a);
      }
  }
  // ---- epilogue: 1/l for accumulator rows via shuffle ----
  const float li0 = 1.0f / l_i[0], li1 = 1.0f / l_i[1];
  #pragma unroll
  for (int rt = 0; rt < 2; ++rt) {
    #pragma unroll
    for (int r = 0; r < 4; ++r) {
      const float inv = __shfl(rt ? li1 : li0, lk8*4 + r, 64);
      const int rowg = rt*16 + lk8*4 + r;
      #pragma unroll
      for (int cc = 0; cc < 3; ++cc) {
        const int colg = (3*wv + cc)*16 + lrow;
        aout[((size_t)(b*TT) + q0 + rowg) * HV + h*VD + colg] = f2bf(acc[rt][cc][r] * inv);
      }
    }
  }
}

extern "C" void kernel_launch(void* const* d_in, const int* in_sizes, int n_in,
                              void* d_out, int out_size, void* d_ws, size_t ws_size,
                              hipStream_t stream)
{
  const float* X   = (const float*)d_in[0];
  const float* Wq  = (const float*)d_in[1];
  const float* Wk  = (const float*)d_in[2];
  const float* Wv  = (const float*)d_in[3];
  const float* Wrk = (const float*)d_in[4];
  const float* We  = (const float*)d_in[5];
  const float* be  = (const float*)d_in[6];
  const float* rwb = (const float*)d_in[7];
  const float* rrb = (const float*)d_in[8];
  float* out = (float*)d_out;

  char* ws = (char*)d_ws;
  ushort* Xb    = (ushort*)ws;                       ws += (size_t)3072*1536*2;
  ushort* Wqkvt = (ushort*)ws;                       ws += (size_t)2560*1536*2;
  ushort* Wet   = (ushort*)ws;                       ws += (size_t)1536*1536*2;
  float*  S1b   = (float*)ws;                        ws += (size_t)97*512*4;
  float*  S2b   = (float*)ws;                        ws += (size_t)97*512*4;
  ushort* qkvb  = (ushort*)ws;                       ws += (size_t)3072*2560*2;
  ushort* vTgb  = (ushort*)ws;                       ws += (size_t)1536*3072*2;
  ushort* rkb   = (ushort*)ws;                       ws += (size_t)3071*512*2;
  float*  c1g   = (float*)ws;                        ws += (size_t)8*3072*4;
  float*  c2g   = (float*)ws;                        ws += (size_t)8*3071*4;
  ushort* ao    = (ushort*)ws;                       // 3072*1536*2

  dim3 blk(256);
  cast_bf16<<<2048, blk, 0, stream>>>(X, Xb, (3072*1536)/4);
  tcast<<<dim3(512/32, 1536/32),  dim3(32,8), 0, stream>>>(Wq, Wqkvt,                      1536, 512,  0.125f*LOG2E);
  tcast<<<dim3(512/32, 1536/32),  dim3(32,8), 0, stream>>>(Wk, Wqkvt + (size_t)512*1536,   1536, 512,  1.0f);
  tcast<<<dim3(1536/32, 1536/32), dim3(32,8), 0, stream>>>(Wv, Wqkvt + (size_t)1024*1536,  1536, 1536, 1.0f);
  tcast<<<dim3(1536/32, 1536/32), dim3(32,8), 0, stream>>>(We, Wet, 1536, 1536, 1.0f);
  wrk_suffix<<<2, blk, 0, stream>>>(Wrk, S1b, S2b);
  relk_fill<<<dim3(2*TT - 1), blk, 0, stream>>>(S1b, S2b, rrb, rkb, c2g);
  gemm_bf16<false, ushort><<<dim3(20, 24), blk, 0, stream>>>(Xb, Wqkvt, nullptr, qkvb, 3072, QKVP, 1536);
  vtrans<<<dim3(1536/32, 3072/32), dim3(32,8), 0, stream>>>(qkvb, vTgb);
  c1_kernel<<<96, blk, 0, stream>>>(qkvb, rwb, c1g);
  attn_mfma<<<dim3(BT*HB*(TT/32)), blk, 0, stream>>>(qkvb, vTgb, rkb, c1g, c2g, ao);
  gemm_bf16<true, float><<<dim3(12, 24), blk, 0, stream>>>(ao, Wet, be, out, 3072, 1536, 1536);
}

// Round 11
// 216.246 us; speedup vs baseline: 1.3112x; 1.1861x over previous
//
#include <hip/hip_runtime.h>
#include <math.h>

#define HB 8
#define KD 64
#define VD 192
#define BT 2
#define TT 1536
#define CC 1536
#define HK (HB*KD)   // 512
#define HV (HB*VD)   // 1536
#define QKVP 2560    // fused qkv row pitch: q[0:512) k[512:1024) v[1024:2560)
#define LOG2E 1.44269504088896340736f

typedef float f32x4 __attribute__((ext_vector_type(4)));
typedef __bf16 bf16x8 __attribute__((ext_vector_type(8)));

static __device__ __forceinline__ ushort f2bf(float f) {
  union { float f; uint u; } v; v.f = f;
  uint r = (v.u + 0x7FFFu + ((v.u >> 16) & 1u)) >> 16;  // RNE
  return (ushort)r;
}
static __device__ __forceinline__ float bf2f(ushort u) {
  union { uint u; float f; } v; v.u = ((uint)u) << 16; return v.f;
}

static __device__ __forceinline__ f32x4 mfma_bf(bf16x8 a, bf16x8 b, f32x4 c) {
  return __builtin_amdgcn_mfma_f32_16x16x32_bf16(a, b, c, 0, 0, 0);
}

static __device__ __forceinline__ void gload_lds16(const ushort* g, ushort* l) {
  __builtin_amdgcn_global_load_lds(
      (const __attribute__((address_space(1))) unsigned int*)g,
      (__attribute__((address_space(3))) unsigned int*)l, 16, 0, 0);
}

__device__ __forceinline__ void storeC(float* p, float v) { *p = v; }
__device__ __forceinline__ void storeC(ushort* p, float v) { *p = f2bf(v); }

// ---------------- cast fp32 -> bf16 (vectorized) ----------------
__global__ __launch_bounds__(256) void cast_bf16(
    const float* __restrict__ in, ushort* __restrict__ out, int n4)
{
  for (int i = blockIdx.x*blockDim.x + threadIdx.x; i < n4; i += gridDim.x*blockDim.x) {
    float4 v = ((const float4*)in)[i];
    ushort4 o; o.x = f2bf(v.x); o.y = f2bf(v.y); o.z = f2bf(v.z); o.w = f2bf(v.w);
    ((ushort4*)out)[i] = o;
  }
}

// ---------------- transpose + cast + scale: in[R][C] fp32 -> out[C][R] bf16 ----------------
__global__ void tcast(const float* __restrict__ in, ushort* __restrict__ out, int R, int C, float scale)
{
  __shared__ float tile[32][33];
  const int bx = blockIdx.x * 32;
  const int by = blockIdx.y * 32;
  const int tx = threadIdx.x, ty = threadIdx.y;  // (32,8)
  #pragma unroll
  for (int i = 0; i < 4; ++i)
    tile[ty + i*8][tx] = in[(size_t)(by + ty + i*8)*C + bx + tx];
  __syncthreads();
  #pragma unroll
  for (int i = 0; i < 4; ++i)
    out[(size_t)(bx + ty + i*8)*R + by + tx] = f2bf(tile[tx][ty + i*8] * scale);
}

// ---------------- bf16 transpose of V section: qkv[key][1024+vd] -> vTg[vd][key] ----------------
__global__ void vtrans(const ushort* __restrict__ in, ushort* __restrict__ out)
{
  __shared__ ushort tile[32][33];
  const int bx = blockIdx.x * 32;  // vd base
  const int by = blockIdx.y * 32;  // key base
  const int tx = threadIdx.x, ty = threadIdx.y;  // (32,8)
  #pragma unroll
  for (int i = 0; i < 4; ++i)
    tile[ty + i*8][tx] = in[(size_t)(by + ty + i*8)*QKVP + 1024 + bx + tx];
  __syncthreads();
  #pragma unroll
  for (int i = 0; i < 4; ++i)
    out[(size_t)(bx + ty + i*8)*(BT*TT) + by + tx] = tile[tx][ty + i*8];
}

// ---------------- bf16 MFMA GEMM: C[M,N] = A[M,Kd] @ Bt[N,Kd]^T (+bias) ----------------
template<bool WITH_BIAS, typename OutT>
__global__ __launch_bounds__(256) void gemm_bf16(
    const ushort* __restrict__ A, const ushort* __restrict__ Bt,
    const float* __restrict__ bias, OutT* __restrict__ C,
    int M, int N, int Kd)
{
  __shared__ __align__(16) ushort As[128*64];
  __shared__ __align__(16) ushort Bs[128*64];
  const int t = threadIdx.x;
  const int w = t >> 6, lane = t & 63;
  const int lrow = lane & 15, lk8 = lane >> 4;
  const int row0 = blockIdx.y * 128, col0 = blockIdx.x * 128;
  const int wr = (w >> 1) * 64, wc = (w & 1) * 64;

  f32x4 acc[4][4];
  #pragma unroll
  for (int m = 0; m < 4; ++m)
    #pragma unroll
    for (int n = 0; n < 4; ++n) acc[m][n] = (f32x4){0.f,0.f,0.f,0.f};

  for (int k0 = 0; k0 < Kd; k0 += 64) {
    __syncthreads();
    #pragma unroll
    for (int j = 0; j < 4; ++j) {
      const int c = (w*4 + j)*64 + lane;
      const int r = c >> 3, cp = c & 7;
      const int sc = cp ^ (r & 7);
      gload_lds16(A  + (size_t)(row0 + r)*Kd + k0 + sc*8, As + c*8);
      gload_lds16(Bt + (size_t)(col0 + r)*Kd + k0 + sc*8, Bs + c*8);
    }
    __syncthreads();
    bf16x8 af[4][2], bfv[4][2];
    #pragma unroll
    for (int m = 0; m < 4; ++m) {
      const int r = wr + m*16 + lrow;
      #pragma unroll
      for (int kh = 0; kh < 2; ++kh) {
        const int k8 = lk8 + kh*4;
        af[m][kh] = *(const bf16x8*)&As[r*64 + ((k8 ^ (r & 7)) << 3)];
      }
    }
    #pragma unroll
    for (int n = 0; n < 4; ++n) {
      const int r = wc + n*16 + lrow;
      #pragma unroll
      for (int kh = 0; kh < 2; ++kh) {
        const int k8 = lk8 + kh*4;
        bfv[n][kh] = *(const bf16x8*)&Bs[r*64 + ((k8 ^ (r & 7)) << 3)];
      }
    }
    #pragma unroll
    for (int m = 0; m < 4; ++m)
      #pragma unroll
      for (int n = 0; n < 4; ++n) {
        acc[m][n] = mfma_bf(af[m][0], bfv[n][0], acc[m][n]);
        acc[m][n] = mfma_bf(af[m][1], bfv[n][1], acc[m][n]);
      }
  }
  #pragma unroll
  for (int m = 0; m < 4; ++m)
    #pragma unroll
    for (int n = 0; n < 4; ++n) {
      const int cg = col0 + wc + n*16 + lrow;
      const float bb = WITH_BIAS ? bias[cg] : 0.f;
      #pragma unroll
      for (int r = 0; r < 4; ++r) {
        const int rg = row0 + wr + m*16 + lk8*4 + r;
        storeC(&C[(size_t)rg*N + cg], acc[m][n][r] + bb);
      }
    }
}

// ---------------- Wrk suffix sums ----------------
__global__ __launch_bounds__(256) void wrk_suffix(
    const float* __restrict__ Wrk, float* __restrict__ S1, float* __restrict__ S2)
{
  const int c = blockIdx.x*blockDim.x + threadIdx.x;
  float a1 = 0.f, a2 = 0.f;
  S1[96*HK + c] = 0.f; S2[96*HK + c] = 0.f;
  for (int i = 95; i >= 0; --i) {
    a1 += Wrk[i*HK + c];
    a2 += Wrk[(96 + i)*HK + c];
    S1[i*HK + c] = a1; S2[i*HK + c] = a2;
  }
}

// ---------------- rk[m][c] bf16 + c2[h][m] = (rrb_h . rk[m]) * log2e ----------------
__global__ __launch_bounds__(256) void relk_fill(
    const float* __restrict__ S1, const float* __restrict__ S2,
    const float* __restrict__ rrb, ushort* __restrict__ rk, float* __restrict__ c2g)
{
  __shared__ float cw[96];
  __shared__ float red[512];
  __shared__ int i0s;
  const int t = threadIdx.x;
  const int m = blockIdx.x;            // 0 .. 2T-2
  if (t < 96) {
    double pr = exp(log((double)(TT + 1)) / 96.0);
    float prf = (float)pr;
    cw[t] = (float)pow((double)prf, (double)(t + 1)) - 1.0f;
  }
  __syncthreads();
  const int d = m - (TT - 1);
  const float ad = fabsf((float)d);
  if (t == 0) {
    int i0 = 96;
    for (int i = 0; i < 96; ++i) if (cw[i] > ad) { i0 = i; break; }
    i0s = i0;
  }
  __syncthreads();
  const float sg = (d > 0) ? 1.f : (d < 0 ? -1.f : 0.f);
  const int i0 = i0s;
  for (int c = t; c < HK; c += 256) {
    const float val = S1[i0*HK + c] + sg * S2[i0*HK + c];
    const ushort vb = f2bf(val);
    rk[(size_t)m * HK + c] = vb;
    red[c] = bf2f(vb) * rrb[c];
  }
  __syncthreads();
  if (t < 8) {
    float s = 0.f;
    #pragma unroll 16
    for (int i = 0; i < 64; ++i) s += red[t*64 + i];
    c2g[(size_t)t*(2*TT - 1) + m] = s * LOG2E;
  }
}

// ---------------- c1[h][row] = (rwb_h . k[row]) * log2e ----------------
__global__ __launch_bounds__(256) void c1_kernel(
    const ushort* __restrict__ qkv, const float* __restrict__ rwb, float* __restrict__ c1g)
{
  const int idx = blockIdx.x*256 + threadIdx.x;  // 3072*8
  const int h = idx & 7, row = idx >> 3;
  const ushort* kr = &qkv[(size_t)row*QKVP + 512 + h*KD];
  float s = 0.f;
  #pragma unroll 16
  for (int c = 0; c < 64; ++c) s += bf2f(kr[c]) * rwb[h*KD + c];
  c1g[h*(BT*TT) + row] = s * LOG2E;
}

// ---------------- fused relative attention: KBLK=64, counted-vmcnt pipeline, XCD-swizzled grid ----------------
// bid = qt*16 + b*8 + h  =>  bid % 8 == h: all 96 blocks of head h land on XCD h
// => per-XCD L2 working set ~2.3 MB (fits 4 MB) instead of the full 28 MB.
__global__ __launch_bounds__(256, 2) void attn_mfma(
    const ushort* __restrict__ qkv, const ushort* __restrict__ vTg,
    const ushort* __restrict__ rk,
    const float* __restrict__ c1g, const float* __restrict__ c2g,
    ushort* __restrict__ aout)
{
  __shared__ __align__(16) ushort ktL[64*64];    // k tile (8 KB)
  __shared__ __align__(16) ushort rkbL[96*64];   // rk band (12 KB), row 95 zero
  __shared__ __align__(16) ushort vTl[192*64];   // vT tile (24 KB)
  __shared__ __align__(16) ushort Pl[32][72];    // probabilities bf16 (4.5 KB)
  __shared__ __align__(16) float S1[32][68];     // content logits (8.5 KB)
  __shared__ __align__(16) float S2[32][98];     // rel logits, 95-wide band (12.25 KB)
  __shared__ float corrl[32], linv[32];

  const int t = threadIdx.x;
  const int wv = t >> 6, lane = t & 63;
  const int lrow = lane & 15, lk8 = lane >> 4;
  const int bid = blockIdx.x;
  const int qt = bid >> 4;          // XCD swizzle: qt in high bits
  const int h  = bid & 7;           // bid%8 == h -> same-head blocks share an XCD
  const int b  = (bid >> 3) & 1;
  const int q0 = qt * 32;

  // q A-fragments (loop-invariant; named regs so rt-select is cndmask, not scratch)
  bf16x8 af00, af01, af10, af11;
  {
    const ushort* qbase = &qkv[((size_t)(b*TT) + q0 + lrow)*QKVP + h*KD];
    af00 = *(const bf16x8*)&qbase[lk8*8];
    af01 = *(const bf16x8*)&qbase[32 + lk8*8];
    af10 = *(const bf16x8*)&qbase[16*QKVP + lk8*8];
    af11 = *(const bf16x8*)&qbase[16*QKVP + 32 + lk8*8];
  }

  if (t < 32) ((uint*)rkbL)[95*32 + t] = 0;   // zero pad row 95

  // ---- per-thread DMA pointers ----
  const ushort* ksrc[2]; ushort* kdst[2];
  #pragma unroll
  for (int W = 0; W < 2; ++W) {
    const int c = W*256 + t;
    const int r = c >> 3, cp = c & 7;
    ksrc[W] = qkv + (size_t)(b*TT + r)*QKVP + 512 + h*KD + (cp ^ (r & 7))*8;
    kdst[W] = ktL + c*8;
  }
  const ushort* rsrc[3]; ushort* rdst[3];
  #pragma unroll
  for (int W = 0; W < 3; ++W) {
    const int c = W*256 + t;
    const int r = c >> 3, cp = c & 7;
    rsrc[W] = rk + (size_t)(1504 - q0 + r)*HK + h*KD + (cp ^ (r & 7))*8;
    rdst[W] = rkbL + c*8;
  }
  const bool rval = t < 248;   // round-2 validity (band row < 95)
  const ushort* vsrc[6]; ushort* vdst[6];
  #pragma unroll
  for (int W = 0; W < 6; ++W) {
    const int c = W*256 + t;
    const int vd = c >> 3, cpk = c & 7;
    vsrc[W] = vTg + (size_t)(h*VD + vd)*(BT*TT) + b*TT + (cpk ^ (vd & 7))*8;
    vdst[W] = vTl + c*8;
  }

  // per-thread S tile columns (loop-invariant)
  int jk_[2], rt1_[2], j2_[3], rt2_[3];
  #pragma unroll
  for (int s = 0; s < 2; ++s) {
    const int idx = wv*2 + s;
    rt1_[s] = idx >> 2; jk_[s] = (idx & 3)*16 + lrow;
  }
  #pragma unroll
  for (int s = 0; s < 3; ++s) {
    const int idx = wv*3 + s;
    rt2_[s] = (idx >= 6) ? 1 : 0; j2_[s] = (idx - 6*rt2_[s])*16 + lrow;
  }

  f32x4 acc[2][3];
  #pragma unroll
  for (int i = 0; i < 2; ++i)
    #pragma unroll
    for (int j = 0; j < 3; ++j) acc[i][j] = (f32x4){0.f, 0.f, 0.f, 0.f};
  float m_i = -1e30f, l_i = 0.f;
  const int r_s = t >> 3;
  const int vsl = t & 7;

  // ---- prologue: prefetch c1/c2(it0), issue k/rkb + vT for it0 ----
  float c1p[2], c2p[3];
  {
    const int mb0 = -q0 + 1504;
    #pragma unroll
    for (int s = 0; s < 2; ++s) c1p[s] = c1g[h*(BT*TT) + b*TT + jk_[s]];
    #pragma unroll
    for (int s = 0; s < 3; ++s) {
      const float v = c2g[(size_t)h*(2*TT - 1) + mb0 + (j2_[s] < 95 ? j2_[s] : 94)];
      c2p[s] = (j2_[s] < 95) ? v : 0.f;
    }
  }
  #pragma unroll
  for (int W = 0; W < 2; ++W) { gload_lds16(ksrc[W], kdst[W]); ksrc[W] += 64*QKVP; }
  gload_lds16(rsrc[0], rdst[0]);           rsrc[0] += 64*HK;
  gload_lds16(rsrc[1], rdst[1]);           rsrc[1] += 64*HK;
  if (rval) gload_lds16(rsrc[2], rdst[2]);
  rsrc[2] += 64*HK;
  #pragma unroll
  for (int W = 0; W < 6; ++W) { gload_lds16(vsrc[W], vdst[W]); vsrc[W] += 64; }

  for (int it = 0; it < 24; ++it) {
    // ==== phase A: S-compute (k/rkb + c1c2 retired; vT still flying) ====
    asm volatile("s_waitcnt vmcnt(6)" ::: "memory");
    __builtin_amdgcn_s_barrier();
    #pragma unroll
    for (int s = 0; s < 2; ++s) {
      const int rt = rt1_[s], jk = jk_[s];
      const bf16x8 a0 = rt ? af10 : af00;
      const bf16x8 a1 = rt ? af11 : af01;
      bf16x8 b0 = *(const bf16x8*)&ktL[jk*64 + ((lk8 ^ (jk & 7)) << 3)];
      bf16x8 b1 = *(const bf16x8*)&ktL[jk*64 + (((lk8 + 4) ^ (jk & 7)) << 3)];
      f32x4 c0 = (f32x4){0.f, 0.f, 0.f, 0.f};
      c0 = mfma_bf(a0, b0, c0);
      c0 = mfma_bf(a1, b1, c0);
      #pragma unroll
      for (int r = 0; r < 4; ++r) S1[rt*16 + lk8*4 + r][jk] = c0[r] + c1p[s];
    }
    #pragma unroll
    for (int s = 0; s < 3; ++s) {
      const int rt = rt2_[s], j2 = j2_[s];
      const bf16x8 a0 = rt ? af10 : af00;
      const bf16x8 a1 = rt ? af11 : af01;
      bf16x8 b0 = *(const bf16x8*)&rkbL[j2*64 + ((lk8 ^ (j2 & 7)) << 3)];
      bf16x8 b1 = *(const bf16x8*)&rkbL[j2*64 + (((lk8 + 4) ^ (j2 & 7)) << 3)];
      f32x4 c0 = (f32x4){0.f, 0.f, 0.f, 0.f};
      c0 = mfma_bf(a0, b0, c0);
      c0 = mfma_bf(a1, b1, c0);
      #pragma unroll
      for (int r = 0; r < 4; ++r) S2[rt*16 + lk8*4 + r][j2] = c0[r] + c2p[s];
    }
    asm volatile("s_waitcnt lgkmcnt(0)" ::: "memory");
    __builtin_amdgcn_s_barrier();

    // ==== phase B: issue next k/rkb + c1c2 prefetch; softmax; retire vT ====
    if (it < 23) {
      #pragma unroll
      for (int W = 0; W < 2; ++W) { gload_lds16(ksrc[W], kdst[W]); ksrc[W] += 64*QKVP; }
      gload_lds16(rsrc[0], rdst[0]);           rsrc[0] += 64*HK;
      gload_lds16(rsrc[1], rdst[1]);           rsrc[1] += 64*HK;
      if (rval) gload_lds16(rsrc[2], rdst[2]);
      rsrc[2] += 64*HK;
      const int kt0n = (it + 1) << 6;
      const int mbn = kt0n - q0 + 1504;
      #pragma unroll
      for (int s = 0; s < 2; ++s) c1p[s] = c1g[h*(BT*TT) + b*TT + kt0n + jk_[s]];
      #pragma unroll
      for (int s = 0; s < 3; ++s) {
        const float v = c2g[(size_t)h*(2*TT - 1) + mbn + (j2_[s] < 95 ? j2_[s] : 94)];
        c2p[s] = (j2_[s] < 95) ? v : 0.f;
      }
    }
    {
      float sv[8];
      #pragma unroll
      for (int i = 0; i < 8; ++i) {
        const int j = vsl*8 + i;
        sv[i] = S1[r_s][j] + S2[r_s][j - r_s + 31];
      }
      float lmax = sv[0];
      #pragma unroll
      for (int i = 1; i < 8; ++i) lmax = fmaxf(lmax, sv[i]);
      #pragma unroll
      for (int s = 1; s < 8; s <<= 1) lmax = fmaxf(lmax, __shfl_xor(lmax, s, 64));
      const bool defer = (lmax <= m_i + 8.0f);
      const float m_new = defer ? m_i : fmaxf(m_i, lmax);
      const float corr  = defer ? 1.0f : exp2f(m_i - m_new);
      float p[8];
      float lsum = 0.f;
      #pragma unroll
      for (int i = 0; i < 8; ++i) { p[i] = exp2f(sv[i] - m_new); lsum += p[i]; }
      uint4 pw;
      pw.x = (uint)f2bf(p[0]) | ((uint)f2bf(p[1]) << 16);
      pw.y = (uint)f2bf(p[2]) | ((uint)f2bf(p[3]) << 16);
      pw.z = (uint)f2bf(p[4]) | ((uint)f2bf(p[5]) << 16);
      pw.w = (uint)f2bf(p[6]) | ((uint)f2bf(p[7]) << 16);
      *(uint4*)&Pl[r_s][vsl*8] = pw;
      #pragma unroll
      for (int s = 1; s < 8; s <<= 1) lsum += __shfl_xor(lsum, s, 64);
      l_i = l_i * corr + lsum;
      m_i = m_new;
      if (vsl == 0) corrl[r_s] = corr;
    }
    if (it < 23) { asm volatile("s_waitcnt vmcnt(10)" ::: "memory"); }
    else         { asm volatile("s_waitcnt vmcnt(0)"  ::: "memory"); }
    asm volatile("s_waitcnt lgkmcnt(0)" ::: "memory");
    __builtin_amdgcn_s_barrier();

    // ==== phase C: PV (operands -> regs, barrier, issue next vT, MFMA) ====
    {
      bf16x8 pa[2][2], bv[3][2];
      #pragma unroll
      for (int rt = 0; rt < 2; ++rt) {
        pa[rt][0] = *(const bf16x8*)&Pl[rt*16 + lrow][lk8*8];
        pa[rt][1] = *(const bf16x8*)&Pl[rt*16 + lrow][32 + lk8*8];
      }
      #pragma unroll
      for (int cc = 0; cc < 3; ++cc) {
        const int rv = (3*wv + cc)*16 + lrow;
        bv[cc][0] = *(const bf16x8*)&vTl[rv*64 + ((lk8 ^ (rv & 7)) << 3)];
        bv[cc][1] = *(const bf16x8*)&vTl[rv*64 + (((lk8 + 4) ^ (rv & 7)) << 3)];
      }
      float cr[2][4];
      #pragma unroll
      for (int rt = 0; rt < 2; ++rt)
        #pragma unroll
        for (int r = 0; r < 4; ++r) cr[rt][r] = corrl[rt*16 + lk8*4 + r];
      asm volatile("s_waitcnt lgkmcnt(0)" ::: "memory");
      __builtin_amdgcn_s_barrier();
      if (it < 23) {
        #pragma unroll
        for (int W = 0; W < 6; ++W) { gload_lds16(vsrc[W], vdst[W]); vsrc[W] += 64; }
      }
      bool need = false;
      #pragma unroll
      for (int rt = 0; rt < 2; ++rt)
        #pragma unroll
        for (int r = 0; r < 4; ++r) need |= (cr[rt][r] != 1.0f);
      if (__any(need ? 1 : 0)) {
        #pragma unroll
        for (int rt = 0; rt < 2; ++rt)
          #pragma unroll
          for (int cc = 0; cc < 3; ++cc)
            #pragma unroll
            for (int r = 0; r < 4; ++r) acc[rt][cc][r] *= cr[rt][r];
      }
      #pragma unroll
      for (int rt = 0; rt < 2; ++rt)
        #pragma unroll
        for (int cc = 0; cc < 3; ++cc) {
          acc[rt][cc] = mfma_bf(pa[rt][0], bv[cc][0], acc[rt][cc]);
          acc[rt][cc] = mfma_bf(pa[rt][1], bv[cc][1], acc[rt][cc]);
        }
    }
  }
  if (vsl == 0) linv[r_s] = 1.0f / l_i;
  __syncthreads();
  #pragma unroll
  for (int rt = 0; rt < 2; ++rt) {
    #pragma unroll
    for (int cc = 0; cc < 3; ++cc) {
      const int colg = (3*wv + cc)*16 + lrow;
      #pragma unroll
      for (int r = 0; r < 4; ++r) {
        const int rowg = rt*16 + lk8*4 + r;
        aout[((size_t)(b*TT) + q0 + rowg) * HV + h*VD + colg] = f2bf(acc[rt][cc][r] * linv[rowg]);
      }
    }
  }
}

extern "C" void kernel_launch(void* const* d_in, const int* in_sizes, int n_in,
                              void* d_out, int out_size, void* d_ws, size_t ws_size,
                              hipStream_t stream)
{
  const float* X   = (const float*)d_in[0];
  const float* Wq  = (const float*)d_in[1];
  const float* Wk  = (const float*)d_in[2];
  const float* Wv  = (const float*)d_in[3];
  const float* Wrk = (const float*)d_in[4];
  const float* We  = (const float*)d_in[5];
  const float* be  = (const float*)d_in[6];
  const float* rwb = (const float*)d_in[7];
  const float* rrb = (const float*)d_in[8];
  float* out = (float*)d_out;

  char* ws = (char*)d_ws;
  ushort* Xb    = (ushort*)ws;                       ws += (size_t)3072*1536*2;
  ushort* Wqkvt = (ushort*)ws;                       ws += (size_t)2560*1536*2;
  ushort* Wet   = (ushort*)ws;                       ws += (size_t)1536*1536*2;
  float*  S1b   = (float*)ws;                        ws += (size_t)97*512*4;
  float*  S2b   = (float*)ws;                        ws += (size_t)97*512*4;
  ushort* qkvb  = (ushort*)ws;                       ws += (size_t)3072*2560*2;
  ushort* vTgb  = (ushort*)ws;                       ws += (size_t)1536*3072*2;
  ushort* rkb   = (ushort*)ws;                       ws += (size_t)3071*512*2;
  float*  c1g   = (float*)ws;                        ws += (size_t)8*3072*4;
  float*  c2g   = (float*)ws;                        ws += (size_t)8*3071*4;
  ushort* ao    = (ushort*)ws;                       // 3072*1536*2

  dim3 blk(256);
  cast_bf16<<<2048, blk, 0, stream>>>(X, Xb, (3072*1536)/4);
  tcast<<<dim3(512/32, 1536/32),  dim3(32,8), 0, stream>>>(Wq, Wqkvt,                      1536, 512,  0.125f*LOG2E);
  tcast<<<dim3(512/32, 1536/32),  dim3(32,8), 0, stream>>>(Wk, Wqkvt + (size_t)512*1536,   1536, 512,  1.0f);
  tcast<<<dim3(1536/32, 1536/32), dim3(32,8), 0, stream>>>(Wv, Wqkvt + (size_t)1024*1536,  1536, 1536, 1.0f);
  tcast<<<dim3(1536/32, 1536/32), dim3(32,8), 0, stream>>>(We, Wet, 1536, 1536, 1.0f);
  wrk_suffix<<<2, blk, 0, stream>>>(Wrk, S1b, S2b);
  relk_fill<<<dim3(2*TT - 1), blk, 0, stream>>>(S1b, S2b, rrb, rkb, c2g);
  gemm_bf16<false, ushort><<<dim3(20, 24), blk, 0, stream>>>(Xb, Wqkvt, nullptr, qkvb, 3072, QKVP, 1536);
  vtrans<<<dim3(1536/32, 3072/32), dim3(32,8), 0, stream>>>(qkvb, vTgb);
  c1_kernel<<<96, blk, 0, stream>>>(qkvb, rwb, c1g);
  attn_mfma<<<dim3(BT*HB*(TT/32)), blk, 0, stream>>>(qkvb, vTgb, rkb, c1g, c2g, ao);
  gemm_bf16<true, float><<<dim3(12, 24), blk, 0, stream>>>(ao, Wet, be, out, 3072, 1536, 1536);
}